// Round 8
// baseline (41.856 us; speedup 1.0000x reference)
//
#include <hip/hip_runtime.h>
#include <math.h>

namespace {
constexpr int kNB  = 16;
constexpr int kNF  = 512;
constexpr int kNTS = 2048;
constexpr int kTPB = 256;                 // 4 waves = 4 bins per block
constexpr int kBinsPerBlock = 4;
constexpr int kChunks = kNTS / 4 / 64;    // 8 float4 chunks per lane
// 1/(8*pi^2) rounded to fp32
constexpr float kC     = 0.012665147955292222f;
constexpr float kTwoPi = 6.28318530717958647692f;

constexpr float kTwoOverPi = 0.636619772367581343f;
constexpr float kP1 = 1.5703125f;               // 201 * 2^-7
constexpr float kP2 = 4.84466552734375e-4f;     // 127 * 2^-18
constexpr float kP3 = -6.407499313354492e-7f;   // -86 * 2^-27
constexpr float kP4 = 9.895302355289459e-10f;   //  68 * 2^-36
}

// Branchless sincos for |x| < 2^17 (args bounded by ~1.3e5).
// fp32 Cody-Waite mod pi/2 (7-bit chunks, k*ci exact for k<2^17) + Cephes
// minimax polys. Error ~4e-7 abs. Bit-identical to the round-3/5 version
// that passes the phase razor (per-element deviation class ~5e-7 vs libm).
__device__ __forceinline__ void fast_sincosf(float x, float& s_out, float& c_out) {
  float kf = rintf(x * kTwoOverPi);
  int   q  = (int)kf;
  float r  = fmaf(-kf, kP1, x);
  r = fmaf(-kf, kP2, r);
  r = fmaf(-kf, kP3, r);
  r = fmaf(-kf, kP4, r);

  float z = r * r;
  float sp = fmaf(fmaf(-1.9515295891e-4f, z, 8.3321608736e-3f), z, -1.6666654611e-1f);
  float s  = fmaf(sp * z, r, r);
  float cp = fmaf(fmaf(2.443315711809948e-5f, z, -1.388731625493765e-3f), z,
                  4.166664568298827e-2f);
  float c  = fmaf(cp, z * z, fmaf(-0.5f, z, 1.0f));

  bool sw = (q & 1) != 0;
  float ss = sw ? c : s;
  float cc = sw ? s : c;
  unsigned sgn_s = (unsigned)(q & 2) << 30;
  unsigned sgn_c = (unsigned)((q + 1) & 2) << 30;
  s_out = __uint_as_float(__float_as_uint(ss) ^ sgn_s);
  c_out = __uint_as_float(__float_as_uint(cc) ^ sgn_c);
}

// One wave (64 lanes) per (b,f) bin; 4 bins per block; no LDS, no syncthreads.
// Nothing stored across passes: pass 2 reloads t,y (L1/L2-hot; total inputs
// 256 KB) and recomputes w. Keeps VGPR low -> 8 waves/SIMD.
__launch_bounds__(kTPB)
__global__ void wavelet_ls_kernel(const float* __restrict__ ys,
                                  const float* __restrict__ ts,
                                  const float* __restrict__ freq,
                                  float* __restrict__ out) {
  const int tid  = threadIdx.x;
  const int wave = tid >> 6;
  const int lane = tid & 63;
  const int bin  = blockIdx.x * kBinsPerBlock + wave;
  const int b    = bin >> 9;            // kNF = 512
  const int f    = bin & (kNF - 1);

  const float* __restrict__ tsb = ts + b * kNTS;
  const float* __restrict__ ysb = ys + b * kNTS;
  const float4* __restrict__ ts4 = (const float4*)tsb;
  const float4* __restrict__ ys4 = (const float4*)ysb;

  const float tau   = 0.5f * (tsb[kNTS / 2] + tsb[kNTS / 2 + 1]);
  const float omega = freq[f] * kTwoPi;

  // Pass-1 accumulators (6): sum_w, w*sin, w*cos, w*(sin*cos), w*(cos^2-sin^2), w*y
  float acc[6];
#pragma unroll
  for (int i = 0; i < 6; ++i) acc[i] = 0.0f;

#pragma unroll
  for (int i = 0; i < kChunks; ++i) {
    const int c = i * 64 + lane;          // coalesced float4 per wave
    const float4 t4 = ts4[c];
    const float4 y4 = ys4[c];
    const float te[4] = {t4.x, t4.y, t4.z, t4.w};
    const float ye[4] = {y4.x, y4.y, y4.z, y4.w};
#pragma unroll
    for (int j = 0; j < 4; ++j) {
      const float t = te[j];
      const float y = ye[j];
      const float dz = omega * (t - tau);      // ref rounding structure, bit-exact
      const float e  = (-kC * dz) * dz;
      const float w  = __expf(e);
      float sn, cs;
      fast_sincosf(omega * t, sn, cs);         // theta = fl(omega*t)
      const float c2 = fmaf(-2.0f * sn, sn, 1.0f);   // cos^2 - sin^2
      acc[0] += w;
      acc[1] = fmaf(w, sn, acc[1]);
      acc[2] = fmaf(w, cs, acc[2]);
      acc[3] = fmaf(w, sn * cs, acc[3]);
      acc[4] = fmaf(w, c2, acc[4]);
      acc[5] = fmaf(w, y, acc[5]);
    }
  }

  // Wave-wide butterfly: all lanes end with the bin totals. No LDS needed.
#pragma unroll
  for (int i = 0; i < 6; ++i) {
    float v = acc[i];
#pragma unroll
    for (int off = 1; off < 64; off <<= 1) v += __shfl_xor(v, off, 64);
    acc[i] = v;
  }

  const float sum_w   = acc[0];
  const float inv_w   = 1.0f / sum_w;
  const float sin_one = acc[1] * inv_w;
  const float cos_one = acc[2] * inv_w;
  const float sin_cos = acc[3] * inv_w;
  const float cc_ss   = acc[4] * inv_w;    // cos_cos - sin_sin
  const float ys_one  = acc[5] * inv_w;

  const float num = 2.0f * (sin_cos - sin_one * cos_one);
  const float den = cc_ss - cos_one * cos_one + sin_one * sin_one;
  const float time_shift = atan2f(num, den) / (2.0f * omega);

  // Pass 2: full per-element recompute of sincos(omega*(t - time_shift)) --
  // the round-6/7 failures proved any cheaper path (sum rotation, Delta-Taylor)
  // perturbs a2 by ~1e-5 and flips the atan2 branch cut at razor bins.
  float a20 = 0.0f, a21 = 0.0f, a22 = 0.0f, a23 = 0.0f;
#pragma unroll
  for (int i = 0; i < kChunks; ++i) {
    const int c = i * 64 + lane;
    const float4 t4 = ts4[c];               // L1-hot reload
    const float4 y4 = ys4[c];
    const float te[4] = {t4.x, t4.y, t4.z, t4.w};
    const float ye[4] = {y4.x, y4.y, y4.z, y4.w};
#pragma unroll
    for (int j = 0; j < 4; ++j) {
      const float t = te[j];
      const float y = ye[j];
      const float dz = omega * (t - tau);      // recompute w (bit-exact path)
      const float e  = (-kC * dz) * dz;
      const float w  = __expf(e);
      float sn, cs;
      fast_sincosf(omega * (t - time_shift), sn, cs);   // ref's phase_arg
      const float wy = w * y;
      a20 = fmaf(w,  cs, a20);    // -> cos_shift_one
      a21 = fmaf(w,  sn, a21);    // -> sin_shift_one
      a22 = fmaf(wy, cs, a22);    // -> ys_cos_shift
      a23 = fmaf(wy, sn, a23);    // -> ys_sin_shift
    }
  }

  {
    float av[4] = {a20, a21, a22, a23};
#pragma unroll
    for (int i = 0; i < 4; ++i) {
      float v = av[i];
#pragma unroll
      for (int off = 1; off < 64; off <<= 1) v += __shfl_xor(v, off, 64);
      av[i] = v;
    }
    a20 = av[0]; a21 = av[1]; a22 = av[2]; a23 = av[3];
  }

  if (lane == 0) {
    const float cos_shift_one = a20 * inv_w;
    const float sin_shift_one = a21 * inv_w;
    const float ys_cos_shift  = a22 * inv_w;
    const float ys_sin_shift  = a23 * inv_w;

    float stc, ctc;
    sincosf(omega * (time_shift - tau), &stc, &ctc);  // once per bin: keep libm

    const float A  = 2.0f * (ys_cos_shift - ys_one * cos_shift_one);
    const float B  = 2.0f * (ys_sin_shift - ys_one * sin_shift_one);
    const float a0 = ys_one;
    const float a1 = ctc * A - stc * B;
    const float a2 = stc * A + ctc * B;
    const float wwp   = a1 * a1 + a2 * a2;
    const float phase = atan2f(a2, a1);

    const int o = b * kNF + f;
    out[0 * kNB * kNF + o] = wwp;
    out[1 * kNB * kNF + o] = phase;
    out[2 * kNB * kNF + o] = a0;
    out[3 * kNB * kNF + o] = a1;
    out[4 * kNB * kNF + o] = a2;
  }
}

extern "C" void kernel_launch(void* const* d_in, const int* in_sizes, int n_in,
                              void* d_out, int out_size, void* d_ws, size_t ws_size,
                              hipStream_t stream) {
  const float* ys   = (const float*)d_in[0];
  const float* ts   = (const float*)d_in[1];
  const float* freq = (const float*)d_in[2];
  float* out = (float*)d_out;

  const int nbins = kNB * kNF;                       // 8192
  dim3 grid(nbins / kBinsPerBlock);                  // 2048 blocks x 4 waves
  wavelet_ls_kernel<<<grid, kTPB, 0, stream>>>(ys, ts, freq, out);
}

// Round 9
// 39.227 us; speedup vs baseline: 1.0670x; 1.0670x over previous
//
#include <hip/hip_runtime.h>
#include <math.h>

namespace {
constexpr int kNB  = 16;
constexpr int kNF  = 512;
constexpr int kNTS = 2048;
constexpr int kTPB = 256;
constexpr int kEPT = kNTS / kTPB;   // 8 elements per thread
constexpr int kVPT = kEPT / 4;      // 2 float4 loads per array
// 1/(8*pi^2) rounded to fp32
constexpr float kC     = 0.012665147955292222f;
constexpr float kTwoPi = 6.28318530717958647692f;

constexpr float kTwoOverPi = 0.636619772367581343f;
constexpr float kP1 = 1.5703125f;               // 201 * 2^-7
constexpr float kP2 = 4.84466552734375e-4f;     // 127 * 2^-18
constexpr float kP3 = -6.407499313354492e-7f;   // -86 * 2^-27
constexpr float kP4 = 9.895302355289459e-10f;   //  68 * 2^-36
}

// Branchless sincos for |x| < 2^17 (args bounded by ~1.3e5).
// fp32 Cody-Waite mod pi/2 (7-bit chunks, k*ci exact for k<2^17) + Cephes
// minimax polys. Error ~4e-7 abs. (Razor-validated: this per-element accuracy
// class passes; ~2e-6-class shortcuts flip the phase branch cut — rounds 6/7.)
__device__ __forceinline__ void fast_sincosf(float x, float& s_out, float& c_out) {
  float kf = rintf(x * kTwoOverPi);
  int   q  = (int)kf;
  float r  = fmaf(-kf, kP1, x);
  r = fmaf(-kf, kP2, r);
  r = fmaf(-kf, kP3, r);
  r = fmaf(-kf, kP4, r);

  float z = r * r;
  float sp = fmaf(fmaf(-1.9515295891e-4f, z, 8.3321608736e-3f), z, -1.6666654611e-1f);
  float s  = fmaf(sp * z, r, r);
  float cp = fmaf(fmaf(2.443315711809948e-5f, z, -1.388731625493765e-3f), z,
                  4.166664568298827e-2f);
  float c  = fmaf(cp, z * z, fmaf(-0.5f, z, 1.0f));

  bool sw = (q & 1) != 0;
  float ss = sw ? c : s;
  float cc = sw ? s : c;
  unsigned sgn_s = (unsigned)(q & 2) << 30;
  unsigned sgn_c = (unsigned)((q + 1) & 2) << 30;
  s_out = __uint_as_float(__float_as_uint(ss) ^ sgn_s);
  c_out = __uint_as_float(__float_as_uint(cc) ^ sgn_c);
}

// Round-3 shape (proven 93% VALUBusy): one 256-thread block per (b,f) bin,
// EPT=8, per-thread arrays live across both passes. __launch_bounds__(256,4)
// gives the allocator ≤128 VGPR headroom instead of self-capping at 40.
__launch_bounds__(kTPB, 4)
__global__ void wavelet_ls_kernel(const float* __restrict__ ys,
                                  const float* __restrict__ ts,
                                  const float* __restrict__ freq,
                                  float* __restrict__ out) {
  const int f    = blockIdx.x;   // frequency index
  const int b    = blockIdx.y;   // batch index
  const int tid  = threadIdx.x;
  const int wave = tid >> 6;

  const float* __restrict__ tsb = ts + b * kNTS;
  const float* __restrict__ ysb = ys + b * kNTS;
  const float4* __restrict__ ts4 = (const float4*)tsb;
  const float4* __restrict__ ys4 = (const float4*)ysb;

  const float tau   = 0.5f * (tsb[kNTS / 2] + tsb[kNTS / 2 + 1]);
  const float omega = freq[f] * kTwoPi;

  // Per-thread sample state kept across both passes.
  float tv[kEPT], wv[kEPT], wyv[kEPT];

  float acc[6];
#pragma unroll
  for (int i = 0; i < 6; ++i) acc[i] = 0.0f;

#pragma unroll
  for (int v = 0; v < kVPT; ++v) {
    const int vidx = v * kTPB + tid;      // coalesced float4
    const float4 t4 = ts4[vidx];
    const float4 y4 = ys4[vidx];
    const float te[4] = {t4.x, t4.y, t4.z, t4.w};
    const float ye[4] = {y4.x, y4.y, y4.z, y4.w};
#pragma unroll
    for (int j = 0; j < 4; ++j) {
      const int k = v * 4 + j;
      const float t = te[j];
      const float y = ye[j];
      tv[k] = t;
      const float dz = omega * (t - tau);      // ref rounding structure, bit-exact
      const float e  = (-kC * dz) * dz;
      const float w  = __expf(e);
      wv[k]  = w;
      wyv[k] = w * y;
      float sn, cs;
      fast_sincosf(omega * t, sn, cs);         // theta = fl(omega*t)
      const float c2 = fmaf(-2.0f * sn, sn, 1.0f);   // cos^2 - sin^2
      acc[0] += w;
      acc[1] = fmaf(w, sn, acc[1]);
      acc[2] = fmaf(w, cs, acc[2]);
      acc[3] = fmaf(w, sn * cs, acc[3]);
      acc[4] = fmaf(w, c2, acc[4]);
      acc[5] = fmaf(w, y, acc[5]);
    }
  }

  // Butterfly within wave; combine the 4 waves via LDS.
  __shared__ float lds1[4][6];
#pragma unroll
  for (int i = 0; i < 6; ++i) {
    float v = acc[i];
#pragma unroll
    for (int off = 1; off < 64; off <<= 1) v += __shfl_xor(v, off, 64);
    if ((tid & 63) == 0) lds1[wave][i] = v;
  }
  __syncthreads();

  float tot[6];
#pragma unroll
  for (int i = 0; i < 6; ++i)
    tot[i] = (lds1[0][i] + lds1[1][i]) + (lds1[2][i] + lds1[3][i]);

  const float sum_w   = tot[0];
  const float inv_w   = 1.0f / sum_w;
  const float sin_one = tot[1] * inv_w;
  const float cos_one = tot[2] * inv_w;
  const float sin_cos = tot[3] * inv_w;
  const float cc_ss   = tot[4] * inv_w;    // cos_cos - sin_sin
  const float ys_one  = tot[5] * inv_w;

  const float num = 2.0f * (sin_cos - sin_one * cos_one);
  const float den = cc_ss - cos_one * cos_one + sin_one * sin_one;
  const float time_shift = atan2f(num, den) / (2.0f * omega);

  // Pass 2: full per-element recompute of sincos(omega*(t - time_shift)).
  // (Rounds 6/7 proved any cheaper path perturbs a2 by ~1e-5 at razor bins
  //  and flips atan2 by 2*pi.)
  float a20 = 0.0f, a21 = 0.0f, a22 = 0.0f, a23 = 0.0f;
#pragma unroll
  for (int k = 0; k < kEPT; ++k) {
    float sn, cs;
    fast_sincosf(omega * (tv[k] - time_shift), sn, cs);   // ref's phase_arg
    const float w  = wv[k];
    const float wy = wyv[k];
    a20 = fmaf(w,  cs, a20);    // -> cos_shift_one
    a21 = fmaf(w,  sn, a21);    // -> sin_shift_one
    a22 = fmaf(wy, cs, a22);    // -> ys_cos_shift
    a23 = fmaf(wy, sn, a23);    // -> ys_sin_shift
  }

  __shared__ float lds2[4][4];
  {
    float av[4] = {a20, a21, a22, a23};
#pragma unroll
    for (int i = 0; i < 4; ++i) {
      float v = av[i];
#pragma unroll
      for (int off = 1; off < 64; off <<= 1) v += __shfl_xor(v, off, 64);
      if ((tid & 63) == 0) lds2[wave][i] = v;
    }
  }
  __syncthreads();

  if (tid == 0) {
    float t2[4];
#pragma unroll
    for (int i = 0; i < 4; ++i)
      t2[i] = (lds2[0][i] + lds2[1][i]) + (lds2[2][i] + lds2[3][i]);

    const float cos_shift_one = t2[0] * inv_w;
    const float sin_shift_one = t2[1] * inv_w;
    const float ys_cos_shift  = t2[2] * inv_w;
    const float ys_sin_shift  = t2[3] * inv_w;

    float stc, ctc;
    sincosf(omega * (time_shift - tau), &stc, &ctc);  // once per block: keep libm

    const float A  = 2.0f * (ys_cos_shift - ys_one * cos_shift_one);
    const float B  = 2.0f * (ys_sin_shift - ys_one * sin_shift_one);
    const float a0 = ys_one;
    const float a1 = ctc * A - stc * B;
    const float a2 = stc * A + ctc * B;
    const float wwp   = a1 * a1 + a2 * a2;
    const float phase = atan2f(a2, a1);

    const int o = b * kNF + f;
    out[0 * kNB * kNF + o] = wwp;
    out[1 * kNB * kNF + o] = phase;
    out[2 * kNB * kNF + o] = a0;
    out[3 * kNB * kNF + o] = a1;
    out[4 * kNB * kNF + o] = a2;
  }
}

extern "C" void kernel_launch(void* const* d_in, const int* in_sizes, int n_in,
                              void* d_out, int out_size, void* d_ws, size_t ws_size,
                              hipStream_t stream) {
  const float* ys   = (const float*)d_in[0];
  const float* ts   = (const float*)d_in[1];
  const float* freq = (const float*)d_in[2];
  float* out = (float*)d_out;

  dim3 grid(kNF, kNB);
  wavelet_ls_kernel<<<grid, kTPB, 0, stream>>>(ys, ts, freq, out);
}